// Round 1
// baseline (126.042 us; speedup 1.0000x reference)
//
#include <hip/hip_runtime.h>

typedef float f32x16 __attribute__((ext_vector_type(16)));
typedef __bf16 bf16x8 __attribute__((ext_vector_type(8)));

__device__ __forceinline__ unsigned short f2bf(float x) {
  unsigned int u = __float_as_uint(x);
  u += 0x7fffu + ((u >> 16) & 1u);   // RTNE
  return (unsigned short)(u >> 16);
}

// ---------------------------------------------------------------------------
// Phase 1: Q = (h@Wq^T + bq)*scale, K = h@Wk^T + bk  (bf16, [32768][96])
//          V^T = (h@Wv^T + bv)^T                      (bf16, [8][96][4096])
// 256 blocks x 256 thr (4 waves, 32 rows each), mfma 32x32x16 bf16.
// ---------------------------------------------------------------------------
__global__ __launch_bounds__(256) void qkv_kernel(
    const float* __restrict__ h,
    const float* __restrict__ Wq, const float* __restrict__ bq,
    const float* __restrict__ Wk, const float* __restrict__ bk,
    const float* __restrict__ Wv, const float* __restrict__ bv,
    unsigned short* __restrict__ Qb, unsigned short* __restrict__ Kb,
    unsigned short* __restrict__ Vt)
{
  __shared__ char sm[128*192 + 3*96*192];
  char* Hsh = sm;
  char* Wsh = sm + 128*192;
  const int tid = threadIdx.x;
  const int blk = blockIdx.x;

  // stage h tile [128][96] f32 -> bf16 LDS (xor-swizzled rows of 192B)
  #pragma unroll
  for (int i = 0; i < 12; ++i) {
    int idx = tid + 256*i;
    int row = idx / 24, c4 = idx % 24;
    float4 v = *(const float4*)(h + ((size_t)blk*128 + row)*96 + c4*4);
    uint2 pk;
    pk.x = f2bf(v.x) | ((unsigned)f2bf(v.y) << 16);
    pk.y = f2bf(v.z) | ((unsigned)f2bf(v.w) << 16);
    *(uint2*)(Hsh + ((row*192 + c4*8) ^ ((row & 7) << 4))) = pk;
  }
  // stage Wq,Wk,Wv [96][96] f32 -> bf16 LDS
  const float* Ws[3] = {Wq, Wk, Wv};
  #pragma unroll 1
  for (int w = 0; w < 3; ++w) {
    const float* W = Ws[w];
    #pragma unroll
    for (int i = 0; i < 9; ++i) {
      int idx = tid + 256*i;
      int row = idx / 24, c4 = idx % 24;
      float4 v = *(const float4*)(W + row*96 + c4*4);
      uint2 pk;
      pk.x = f2bf(v.x) | ((unsigned)f2bf(v.y) << 16);
      pk.y = f2bf(v.z) | ((unsigned)f2bf(v.w) << 16);
      *(uint2*)(Wsh + w*18432 + ((row*192 + c4*8) ^ ((row & 7) << 4))) = pk;
    }
  }
  __syncthreads();

  const int lane = tid & 63, wv = tid >> 6, hi = lane >> 5, ln = lane & 31;
  const int mrow0 = wv * 32;

  bf16x8 af[6];
  #pragma unroll
  for (int c = 0; c < 6; ++c)
    af[c] = *(const bf16x8*)(Hsh + (((mrow0 + ln)*192 + c*32 + hi*16) ^ ((ln & 7) << 4)));

  const float* biases[3] = {bq, bk, bv};
  #pragma unroll 1
  for (int w = 0; w < 3; ++w) {
    f32x16 acc[3];
    #pragma unroll
    for (int j = 0; j < 3; ++j)
      #pragma unroll
      for (int r = 0; r < 16; ++r) acc[j][r] = 0.f;

    #pragma unroll
    for (int c = 0; c < 6; ++c) {
      #pragma unroll
      for (int j = 0; j < 3; ++j) {
        bf16x8 bfr = *(const bf16x8*)(Wsh + w*18432 +
                      (((ln + 32*j)*192 + c*32 + hi*16) ^ ((ln & 7) << 4)));
        acc[j] = __builtin_amdgcn_mfma_f32_32x32x16_bf16(af[c], bfr, acc[j], 0, 0, 0);
      }
    }
    #pragma unroll
    for (int j = 0; j < 3; ++j) {
      const int e = ln + 32*j;
      const float bias = biases[w][e];
      if (w == 2) {
        // V^T store: 4 consecutive s per uint2
        #pragma unroll
        for (int g = 0; g < 4; ++g) {
          unsigned short s4[4];
          #pragma unroll
          for (int rr = 0; rr < 4; ++rr) s4[rr] = f2bf(acc[j][4*g + rr] + bias);
          int srow = blk*128 + mrow0 + 8*g + 4*hi;
          int b = srow >> 12, s = srow & 4095;
          uint2 pk;
          pk.x = s4[0] | ((unsigned)s4[1] << 16);
          pk.y = s4[2] | ((unsigned)s4[3] << 16);
          *(uint2*)(Vt + ((size_t)b*96 + e)*4096 + s) = pk;
        }
      } else {
        unsigned short* Outp = (w == 0) ? Qb : Kb;
        const float sc = (w == 0) ? 0.102062072615966f : 1.0f;  // 1/sqrt(96)
        #pragma unroll
        for (int r = 0; r < 16; ++r) {
          int grow = blk*128 + mrow0 + (r & 3) + 8*(r >> 2) + 4*hi;
          Outp[(size_t)grow*96 + e] = f2bf((acc[j][r] + bias) * sc);
        }
      }
    }
  }
}

// ---------------------------------------------------------------------------
// Phase 2: flash attention, swapped operands (S^T = K*Q, O^T = V^T * P^T).
// grid (16,8,2) x 512thr. Each wave: 32 q-rows; KV tiles of 64 staged in LDS.
// Outputs unnormalized O + (m,l) per row per kv-split.
// ---------------------------------------------------------------------------
__global__ __launch_bounds__(512, 2) void flash_kernel(
    const unsigned short* __restrict__ Qb, const unsigned short* __restrict__ Kb,
    const unsigned short* __restrict__ Vt, float* __restrict__ Op,
    float* __restrict__ ml)
{
  __shared__ char sm[24576];
  char* Ksh = sm;            // [64][96] bf16, row xor-swizzle ((t&7)<<4)
  char* Vsh = sm + 12288;    // [96][64] bf16 (V^T), row xor-swizzle ((e&7)<<4)
  const int tid = threadIdx.x;
  const int lane = tid & 63, wv = tid >> 6, hi = lane >> 5, ln = lane & 31;
  const int qt = blockIdx.x, bb = blockIdx.y, sp = blockIdx.z;
  const int q0 = qt*256 + wv*32;
  const size_t qrow = (size_t)bb*4096 + q0 + ln;

  bf16x8 qf[6];
  #pragma unroll
  for (int c = 0; c < 6; ++c)
    qf[c] = *(const bf16x8*)(Qb + qrow*96 + c*16 + hi*8);

  f32x16 accO[3];
  #pragma unroll
  for (int j = 0; j < 3; ++j)
    #pragma unroll
    for (int r = 0; r < 16; ++r) accO[j][r] = 0.f;

  float m = -1e30f, l = 0.f;
  const int sbase = sp * 2048;

  for (int st = 0; st < 32; ++st) {
    const int s0 = sbase + st*64;
    __syncthreads();
    {
      // 1536 x 16B chunks: [0,768)=K tile, [768,1536)=V^T tile. Coalesced.
      {
        int t = tid / 12, ch = tid % 12;
        uint4 d = *(const uint4*)(Kb + ((size_t)bb*4096 + s0 + t)*96 + ch*8);
        *(uint4*)(Ksh + ((t*192 + ch*16) ^ ((t & 7) << 4))) = d;
      }
      {
        int idx = tid + 512;
        if (idx < 768) {
          int t = idx / 12, ch = idx % 12;
          uint4 d = *(const uint4*)(Kb + ((size_t)bb*4096 + s0 + t)*96 + ch*8);
          *(uint4*)(Ksh + ((t*192 + ch*16) ^ ((t & 7) << 4))) = d;
        } else {
          int v = idx - 768, e = v >> 3, ch = v & 7;
          uint4 d = *(const uint4*)(Vt + ((size_t)bb*96 + e)*4096 + s0 + ch*8);
          *(uint4*)(Vsh + ((e*128 + ch*16) ^ ((e & 7) << 4))) = d;
        }
      }
      {
        int v = tid + 1024 - 768, e = v >> 3, ch = v & 7;
        uint4 d = *(const uint4*)(Vt + ((size_t)bb*96 + e)*4096 + s0 + ch*8);
        *(uint4*)(Vsh + ((e*128 + ch*16) ^ ((e & 7) << 4))) = d;
      }
    }
    __syncthreads();

    // S^T = K * Q  (col = lane&31 = q ; rows = t via crow(r,hi))
    f32x16 sA, sB;
    #pragma unroll
    for (int r = 0; r < 16; ++r) { sA[r] = 0.f; sB[r] = 0.f; }
    #pragma unroll
    for (int c = 0; c < 6; ++c) {
      bf16x8 k0 = *(const bf16x8*)(Ksh + ((ln*192 + c*32 + hi*16) ^ ((ln & 7) << 4)));
      bf16x8 k1 = *(const bf16x8*)(Ksh + (((ln + 32)*192 + c*32 + hi*16) ^ ((ln & 7) << 4)));
      sA = __builtin_amdgcn_mfma_f32_32x32x16_bf16(k0, qf[c], sA, 0, 0, 0);
      sB = __builtin_amdgcn_mfma_f32_32x32x16_bf16(k1, qf[c], sB, 0, 0, 0);
    }

    // online softmax (per-lane q; halves merged with lane^32 partner)
    float mx = -1e30f;
    #pragma unroll
    for (int r = 0; r < 16; ++r) { mx = fmaxf(mx, sA[r]); mx = fmaxf(mx, sB[r]); }
    mx = fmaxf(mx, __shfl_xor(mx, 32, 64));
    const float mnew = fmaxf(m, mx);
    const float alpha = __expf(m - mnew);
    float p[32];
    float sum = 0.f;
    #pragma unroll
    for (int r = 0; r < 16; ++r) { p[r] = __expf(sA[r] - mnew); sum += p[r]; }
    #pragma unroll
    for (int r = 0; r < 16; ++r) { p[16 + r] = __expf(sB[r] - mnew); sum += p[16 + r]; }
    sum += __shfl_xor(sum, 32, 64);
    l = l * alpha + sum;
    m = mnew;
    #pragma unroll
    for (int j = 0; j < 3; ++j)
      #pragma unroll
      for (int r = 0; r < 16; ++r) accO[j][r] *= alpha;

    // pack P^T B-frags in-register (k-chunk c1 covers t in [16*c1,16*c1+16))
    bf16x8 pf[4];
    #pragma unroll
    for (int c1 = 0; c1 < 4; ++c1) {
      union { bf16x8 v; unsigned short u[8]; } f;
      #pragma unroll
      for (int i = 0; i < 8; ++i)
        f.u[i] = f2bf(p[(c1 >> 1)*16 + (c1 & 1)*8 + i]);
      pf[c1] = f.v;
    }

    // O^T += V^T * P^T
    #pragma unroll
    for (int c1 = 0; c1 < 4; ++c1) {
      #pragma unroll
      for (int j = 0; j < 3; ++j) {
        const int e = ln + 32*j;
        const int base = e*128 + c1*32 + hi*8;
        const int sw = (e & 7) << 4;
        union { bf16x8 v; uint2 d2[2]; } f;
        f.d2[0] = *(const uint2*)(Vsh + (base ^ sw));
        f.d2[1] = *(const uint2*)(Vsh + ((base + 16) ^ sw));
        accO[j] = __builtin_amdgcn_mfma_f32_32x32x16_bf16(f.v, pf[c1], accO[j], 0, 0, 0);
      }
    }
  }

  // epilogue: unnormalized partial O (col=q per-lane, rows e=crow+32j)
  float* Oprow = Op + ((size_t)sp*32768 + qrow)*96;
  #pragma unroll
  for (int j = 0; j < 3; ++j)
    #pragma unroll
    for (int g = 0; g < 4; ++g) {
      float4 o = make_float4(accO[j][4*g+0], accO[j][4*g+1], accO[j][4*g+2], accO[j][4*g+3]);
      *(float4*)(Oprow + 32*j + 8*g + 4*hi) = o;
    }
  if (hi == 0) {
    ml[((size_t)sp*2 + 0)*32768 + qrow] = m;
    ml[((size_t)sp*2 + 1)*32768 + qrow] = l;
  }
}

// ---------------------------------------------------------------------------
// Phase 3: combine the 2 kv-splits per row and normalize.
// ---------------------------------------------------------------------------
__global__ __launch_bounds__(256) void combine_kernel(
    const float* __restrict__ Op, const float* __restrict__ ml,
    float* __restrict__ out)
{
  const int g = blockIdx.x*256 + threadIdx.x;      // 32768*24 items
  const int row = g / 24, e4 = (g % 24)*4;
  const float m0 = ml[row],          l0 = ml[32768 + row];
  const float m1 = ml[65536 + row],  l1 = ml[98304 + row];
  const float mm = fmaxf(m0, m1);
  const float w0 = __expf(m0 - mm), w1 = __expf(m1 - mm);
  const float inv = 1.0f / (w0*l0 + w1*l1);
  const float4 a = *(const float4*)(Op + (size_t)row*96 + e4);
  const float4 b = *(const float4*)(Op + 3145728 + (size_t)row*96 + e4);
  float4 o;
  o.x = (w0*a.x + w1*b.x) * inv;
  o.y = (w0*a.y + w1*b.y) * inv;
  o.z = (w0*a.z + w1*b.z) * inv;
  o.w = (w0*a.w + w1*b.w) * inv;
  *(float4*)(out + (size_t)row*96 + e4) = o;
}

extern "C" void kernel_launch(void* const* d_in, const int* in_sizes, int n_in,
                              void* d_out, int out_size, void* d_ws, size_t ws_size,
                              hipStream_t stream) {
  const float* h  = (const float*)d_in[0];
  const float* Wq = (const float*)d_in[1];
  const float* bq = (const float*)d_in[2];
  const float* Wk = (const float*)d_in[3];
  const float* bk = (const float*)d_in[4];
  const float* Wv = (const float*)d_in[5];
  const float* bv = (const float*)d_in[6];
  float* out = (float*)d_out;
  char* ws = (char*)d_ws;
  // ws layout (44.6 MB total):
  unsigned short* Qb = (unsigned short*)(ws);             // 6.29 MB
  unsigned short* Kb = (unsigned short*)(ws + 6291456);   // 6.29 MB
  unsigned short* Vt = (unsigned short*)(ws + 12582912);  // 6.29 MB
  float*          Op = (float*)(ws + 18874368);           // 25.2 MB
  float*          mlp= (float*)(ws + 44040192);           // 0.52 MB

  qkv_kernel<<<256, 256, 0, stream>>>(h, Wq, bq, Wk, bk, Wv, bv, Qb, Kb, Vt);
  flash_kernel<<<dim3(16, 8, 2), 512, 0, stream>>>(Qb, Kb, Vt, Op, mlp);
  combine_kernel<<<3072, 256, 0, stream>>>(Op, mlp, out);
}

// Round 2
// 109.774 us; speedup vs baseline: 1.1482x; 1.1482x over previous
//
#include <hip/hip_runtime.h>

typedef float f32x16 __attribute__((ext_vector_type(16)));
typedef __bf16 bf16x8 __attribute__((ext_vector_type(8)));

__device__ __forceinline__ unsigned short f2bf(float x) {
  union { __bf16 b; unsigned short u; } c; c.b = (__bf16)x; return c.u;
}
__device__ __forceinline__ unsigned pk2(float a, float b) {
  union { __bf16 h[2]; unsigned u; } c;
  c.h[0] = (__bf16)a; c.h[1] = (__bf16)b;
  return c.u;
}

// ---------------------------------------------------------------------------
// Phase 1: Q = (h@Wq^T + bq)*scale*log2e, K = h@Wk^T + bk  (bf16, [32768][96])
//          V^T = (h@Wv^T + bv)^T                            (bf16, [8][96][4096])
// ---------------------------------------------------------------------------
__global__ __launch_bounds__(256) void qkv_kernel(
    const float* __restrict__ h,
    const float* __restrict__ Wq, const float* __restrict__ bq,
    const float* __restrict__ Wk, const float* __restrict__ bk,
    const float* __restrict__ Wv, const float* __restrict__ bv,
    unsigned short* __restrict__ Qb, unsigned short* __restrict__ Kb,
    unsigned short* __restrict__ Vt)
{
  __shared__ char sm[128*192 + 3*96*192];
  char* Hsh = sm;
  char* Wsh = sm + 128*192;
  const int tid = threadIdx.x;
  const int blk = blockIdx.x;

  #pragma unroll
  for (int i = 0; i < 12; ++i) {
    int idx = tid + 256*i;
    int row = idx / 24, c4 = idx % 24;
    float4 v = *(const float4*)(h + ((size_t)blk*128 + row)*96 + c4*4);
    uint2 pk;
    pk.x = pk2(v.x, v.y);
    pk.y = pk2(v.z, v.w);
    *(uint2*)(Hsh + ((row*192 + c4*8) ^ ((row & 7) << 4))) = pk;
  }
  const float* Ws[3] = {Wq, Wk, Wv};
  #pragma unroll 1
  for (int w = 0; w < 3; ++w) {
    const float* W = Ws[w];
    #pragma unroll
    for (int i = 0; i < 9; ++i) {
      int idx = tid + 256*i;
      int row = idx / 24, c4 = idx % 24;
      float4 v = *(const float4*)(W + row*96 + c4*4);
      uint2 pk;
      pk.x = pk2(v.x, v.y);
      pk.y = pk2(v.z, v.w);
      *(uint2*)(Wsh + w*18432 + ((row*192 + c4*8) ^ ((row & 7) << 4))) = pk;
    }
  }
  __syncthreads();

  const int lane = tid & 63, wv = tid >> 6, hi = lane >> 5, ln = lane & 31;
  const int mrow0 = wv * 32;

  bf16x8 af[6];
  #pragma unroll
  for (int c = 0; c < 6; ++c)
    af[c] = *(const bf16x8*)(Hsh + (((mrow0 + ln)*192 + c*32 + hi*16) ^ ((ln & 7) << 4)));

  const float* biases[3] = {bq, bk, bv};
  #pragma unroll 1
  for (int w = 0; w < 3; ++w) {
    f32x16 acc[3];
    #pragma unroll
    for (int j = 0; j < 3; ++j)
      #pragma unroll
      for (int r = 0; r < 16; ++r) acc[j][r] = 0.f;

    #pragma unroll
    for (int c = 0; c < 6; ++c) {
      #pragma unroll
      for (int j = 0; j < 3; ++j) {
        bf16x8 bfr = *(const bf16x8*)(Wsh + w*18432 +
                      (((ln + 32*j)*192 + c*32 + hi*16) ^ ((ln & 7) << 4)));
        acc[j] = __builtin_amdgcn_mfma_f32_32x32x16_bf16(af[c], bfr, acc[j], 0, 0, 0);
      }
    }
    #pragma unroll
    for (int j = 0; j < 3; ++j) {
      const int e = ln + 32*j;
      const float bias = biases[w][e];
      if (w == 2) {
        #pragma unroll
        for (int g = 0; g < 4; ++g) {
          int srow = blk*128 + mrow0 + 8*g + 4*hi;
          int b = srow >> 12, s = srow & 4095;
          uint2 pk;
          pk.x = pk2(acc[j][4*g+0] + bias, acc[j][4*g+1] + bias);
          pk.y = pk2(acc[j][4*g+2] + bias, acc[j][4*g+3] + bias);
          *(uint2*)(Vt + ((size_t)b*96 + e)*4096 + s) = pk;
        }
      } else {
        unsigned short* Outp = (w == 0) ? Qb : Kb;
        // Q scale = (1/sqrt(96)) * log2(e) so softmax runs in exp2 domain
        const float sc = (w == 0) ? 0.14724443849485857f : 1.0f;
        #pragma unroll
        for (int r = 0; r < 16; ++r) {
          int grow = blk*128 + mrow0 + (r & 3) + 8*(r >> 2) + 4*hi;
          Outp[(size_t)grow*96 + e] = f2bf((acc[j][r] + bias) * sc);
        }
      }
    }
  }
}

// ---------------------------------------------------------------------------
// Phase 2: flash attention, swapped operands (S^T = K*Q, O^T = V^T * P^T).
// grid (32,8,2) x 256thr (4 waves, 32 q-rows each). KV tiles of 64, async
// double-buffered LDS (issue loads -> compute -> LDS write -> 1 barrier).
// Softmax in exp2 domain (scale folded into Q). V stored in LDS with
// permuted-t layout so PV A-frags are single conflict-free b128 reads.
// ---------------------------------------------------------------------------
#define NT 32
__global__ __launch_bounds__(256, 2) void flash_kernel(
    const unsigned short* __restrict__ Qb, const unsigned short* __restrict__ Kb,
    const unsigned short* __restrict__ Vt, float* __restrict__ Op,
    float* __restrict__ ml)
{
  __shared__ char sm[2*24576];   // per buf: K [64][96]swz @0, Vperm [96][64] @12288
  const int tid = threadIdx.x;
  const int lane = tid & 63, wv = tid >> 6, hi = lane >> 5, ln = lane & 31;
  const int qt = blockIdx.x, bb = blockIdx.y, sp = blockIdx.z;
  const int q0 = qt*128 + wv*32;
  const size_t qrow = (size_t)bb*4096 + q0 + ln;
  const int sbase = sp * 2048;

  // Q fragments (k-major, 16 elems per frag, 8 per lane-half)
  bf16x8 qf[6];
  #pragma unroll
  for (int c = 0; c < 6; ++c)
    qf[c] = *(const bf16x8*)(Qb + qrow*96 + c*16 + hi*8);

  // ---- staging geometry: 768 K-chunks + 768 V-chunks of 16B, 6 per thread
  const unsigned short* kg[3];
  const unsigned short* vg[3];
  int koff[3], voffA[3], voffB[3];
  #pragma unroll
  for (int i = 0; i < 3; ++i) {
    int c = tid + 256*i;
    int krow = c / 12, kch = c % 12;
    kg[i] = Kb + ((size_t)bb*4096 + sbase + krow)*96 + kch*8;
    koff[i] = (krow*192 + kch*16) ^ ((krow & 7) << 4);
    int e = c >> 3, vch = c & 7;
    vg[i] = Vt + ((size_t)bb*96 + e)*4096 + sbase + vch*8;
    int vbase = e*128 + (vch >> 1)*32 + (vch & 1)*8;
    int vsw = (e & 7) << 4;
    voffA[i] = vbase ^ vsw;
    voffB[i] = (vbase + 16) ^ vsw;
  }

  uint4 kreg[3], vreg[3];
  #pragma unroll
  for (int i = 0; i < 3; ++i) {
    kreg[i] = *(const uint4*)kg[i]; kg[i] += 64*96;
    vreg[i] = *(const uint4*)vg[i]; vg[i] += 64;
  }
  // write tile 0 into buf 0
  #pragma unroll
  for (int i = 0; i < 3; ++i) {
    *(uint4*)(sm + koff[i]) = kreg[i];
    *(uint2*)(sm + 12288 + voffA[i]) = make_uint2(vreg[i].x, vreg[i].y);
    *(uint2*)(sm + 12288 + voffB[i]) = make_uint2(vreg[i].z, vreg[i].w);
  }
  __syncthreads();

  f32x16 accO[3];
  #pragma unroll
  for (int j = 0; j < 3; ++j)
    #pragma unroll
    for (int r = 0; r < 16; ++r) accO[j][r] = 0.f;

  float m = -1e30f, l = 0.f;

  for (int st = 0; st < NT; ++st) {
    char* Ksh = sm + (st & 1)*24576;
    char* Vsh = Ksh + 12288;
    char* Ksh_n = sm + ((st & 1) ^ 1)*24576;
    char* Vsh_n = Ksh_n + 12288;

    // issue next tile's global loads (latency hides under compute below)
    if (st + 1 < NT) {
      #pragma unroll
      for (int i = 0; i < 3; ++i) {
        kreg[i] = *(const uint4*)kg[i]; kg[i] += 64*96;
        vreg[i] = *(const uint4*)vg[i]; vg[i] += 64;
      }
    }

    // S^T = K * Q  (col = lane&31 = q ; rows = t)
    f32x16 sA, sB;
    #pragma unroll
    for (int r = 0; r < 16; ++r) { sA[r] = 0.f; sB[r] = 0.f; }
    #pragma unroll
    for (int c = 0; c < 6; ++c) {
      bf16x8 k0 = *(const bf16x8*)(Ksh + ((ln*192 + c*32 + hi*16) ^ ((ln & 7) << 4)));
      bf16x8 k1 = *(const bf16x8*)(Ksh + (((ln + 32)*192 + c*32 + hi*16) ^ ((ln & 7) << 4)));
      sA = __builtin_amdgcn_mfma_f32_32x32x16_bf16(k0, qf[c], sA, 0, 0, 0);
      sB = __builtin_amdgcn_mfma_f32_32x32x16_bf16(k1, qf[c], sB, 0, 0, 0);
    }

    // online softmax in exp2 domain (per-lane q; halves merged via lane^32)
    float mx = -1e30f;
    #pragma unroll
    for (int r = 0; r < 16; ++r) { mx = fmaxf(mx, sA[r]); mx = fmaxf(mx, sB[r]); }
    mx = fmaxf(mx, __shfl_xor(mx, 32, 64));
    if (__any(mx > m)) {          // exact defer: skipped iff alpha==1 for all lanes
      const float mnew = fmaxf(m, mx);
      const float alpha = __builtin_amdgcn_exp2f(m - mnew);
      #pragma unroll
      for (int j = 0; j < 3; ++j)
        #pragma unroll
        for (int r = 0; r < 16; ++r) accO[j][r] *= alpha;
      l *= alpha;
      m = mnew;
    }
    float p[32];
    float sum = 0.f;
    #pragma unroll
    for (int r = 0; r < 16; ++r) { p[r] = __builtin_amdgcn_exp2f(sA[r] - m); sum += p[r]; }
    #pragma unroll
    for (int r = 0; r < 16; ++r) { p[16+r] = __builtin_amdgcn_exp2f(sB[r] - m); sum += p[16+r]; }
    sum += __shfl_xor(sum, 32, 64);
    l += sum;

    // pack P^T B-frags (k-chunk c1 covers t in [16*c1,16*c1+16))
    union { bf16x8 v; unsigned u32[4]; } pf[4];
    #pragma unroll
    for (int c1 = 0; c1 < 4; ++c1) {
      const int b = (c1 >> 1)*16 + (c1 & 1)*8;
      #pragma unroll
      for (int k = 0; k < 4; ++k)
        pf[c1].u32[k] = pk2(p[b + 2*k], p[b + 2*k + 1]);
    }

    // O^T += V^T * P^T  (V frag = single b128, permuted-t layout)
    #pragma unroll
    for (int c1 = 0; c1 < 4; ++c1) {
      #pragma unroll
      for (int j = 0; j < 3; ++j) {
        const int e = ln + 32*j;
        bf16x8 vf = *(const bf16x8*)(Vsh + ((e*128 + c1*32 + hi*16) ^ ((e & 7) << 4)));
        accO[j] = __builtin_amdgcn_mfma_f32_32x32x16_bf16(vf, pf[c1].v, accO[j], 0, 0, 0);
      }
    }

    // write staged regs into the other buffer (its last readers were iter st-1,
    // already separated by that iteration's barrier)
    if (st + 1 < NT) {
      #pragma unroll
      for (int i = 0; i < 3; ++i) {
        *(uint4*)(Ksh_n + koff[i]) = kreg[i];
        *(uint2*)(Vsh_n + voffA[i]) = make_uint2(vreg[i].x, vreg[i].y);
        *(uint2*)(Vsh_n + voffB[i]) = make_uint2(vreg[i].z, vreg[i].w);
      }
    }
    __syncthreads();
  }

  // epilogue: unnormalized partial O (col=q per-lane, rows e)
  float* Oprow = Op + ((size_t)sp*32768 + qrow)*96;
  #pragma unroll
  for (int j = 0; j < 3; ++j)
    #pragma unroll
    for (int g = 0; g < 4; ++g) {
      float4 o = make_float4(accO[j][4*g+0], accO[j][4*g+1], accO[j][4*g+2], accO[j][4*g+3]);
      *(float4*)(Oprow + 32*j + 8*g + 4*hi) = o;
    }
  if (hi == 0) {
    ml[((size_t)sp*2 + 0)*32768 + qrow] = m;
    ml[((size_t)sp*2 + 1)*32768 + qrow] = l;
  }
}

// ---------------------------------------------------------------------------
// Phase 3: combine the 2 kv-splits per row and normalize (exp2 domain).
// ---------------------------------------------------------------------------
__global__ __launch_bounds__(256) void combine_kernel(
    const float* __restrict__ Op, const float* __restrict__ ml,
    float* __restrict__ out)
{
  const int g = blockIdx.x*256 + threadIdx.x;
  const int row = g / 24, e4 = (g % 24)*4;
  const float m0 = ml[row],          l0 = ml[32768 + row];
  const float m1 = ml[65536 + row],  l1 = ml[98304 + row];
  const float mm = fmaxf(m0, m1);
  const float w0 = __builtin_amdgcn_exp2f(m0 - mm);
  const float w1 = __builtin_amdgcn_exp2f(m1 - mm);
  const float inv = 1.0f / (w0*l0 + w1*l1);
  const float4 a = *(const float4*)(Op + (size_t)row*96 + e4);
  const float4 b = *(const float4*)(Op + 3145728 + (size_t)row*96 + e4);
  float4 o;
  o.x = (w0*a.x + w1*b.x) * inv;
  o.y = (w0*a.y + w1*b.y) * inv;
  o.z = (w0*a.z + w1*b.z) * inv;
  o.w = (w0*a.w + w1*b.w) * inv;
  *(float4*)(out + (size_t)row*96 + e4) = o;
}

extern "C" void kernel_launch(void* const* d_in, const int* in_sizes, int n_in,
                              void* d_out, int out_size, void* d_ws, size_t ws_size,
                              hipStream_t stream) {
  const float* h  = (const float*)d_in[0];
  const float* Wq = (const float*)d_in[1];
  const float* bq = (const float*)d_in[2];
  const float* Wk = (const float*)d_in[3];
  const float* bk = (const float*)d_in[4];
  const float* Wv = (const float*)d_in[5];
  const float* bv = (const float*)d_in[6];
  float* out = (float*)d_out;
  char* ws = (char*)d_ws;
  unsigned short* Qb = (unsigned short*)(ws);             // 6.29 MB
  unsigned short* Kb = (unsigned short*)(ws + 6291456);   // 6.29 MB
  unsigned short* Vt = (unsigned short*)(ws + 12582912);  // 6.29 MB
  float*          Op = (float*)(ws + 18874368);           // 25.2 MB
  float*          mlp= (float*)(ws + 44040192);           // 0.52 MB

  qkv_kernel<<<256, 256, 0, stream>>>(h, Wq, bq, Wk, bk, Wv, bv, Qb, Kb, Vt);
  flash_kernel<<<dim3(32, 8, 2), 256, 0, stream>>>(Qb, Kb, Vt, Op, mlp);
  combine_kernel<<<3072, 256, 0, stream>>>(Op, mlp, out);
}